// Round 6
// baseline (499.238 us; speedup 1.0000x reference)
//
#include <hip/hip_runtime.h>
#include <hip/hip_cooperative_groups.h>
#include <math.h>

namespace cg = cooperative_groups;

typedef unsigned short u16;
typedef __attribute__((ext_vector_type(8))) short bf16x8;
typedef __attribute__((ext_vector_type(4))) float f32x4;

#define N 2048
#define D 256
#define PAIRS 8
#define NO 2049
#define MASKVAL -3.0e38f          // stored sentinel: finite in bf16
#define LDA 72                    // proj padded LDS row stride (u16), 144B (16B-mult)
#define LDST 136                  // epilogue stage row stride (u16), 16B-mult

// ws float region (float offsets within wsf) — layout as R4
#define WS_LS0   0
#define WS_LS1   (1*PAIRS*N)
#define WS_LSN0  (2*PAIRS*N)
#define WS_LSN1  (3*PAIRS*N)
#define WS_CST   (6*PAIRS*N)               // packed col stats {colA,s1} [PAIRS][N][2]
#define WS_RPM   (8*PAIRS*N)               // row partials max [PAIRS][16][N]
#define WS_RPS   (WS_RPM + PAIRS*16*N)
#define WS_CPM   (WS_RPS + PAIRS*16*N)     // col partials max [PAIRS][16][N]
#define WS_CPS   (WS_CPM + PAIRS*16*N)
#define WS_ROW   (WS_CPS + PAIRS*16*N)     // packed row stats {rc,l0,ln0,0} [PAIRS][N][4]
#define WS_F_COUNT (WS_ROW + 4*PAIRS*N)

__device__ __forceinline__ float b2f(u16 u) {
    return __uint_as_float(((unsigned)u) << 16);
}
__device__ __forceinline__ u16 f2b(float f) {  // RNE f32->bf16 (finite in)
    unsigned x = __float_as_uint(f);
    x += 0x7FFFu + ((x >> 16) & 1u);
    return (u16)(x >> 16);
}
__device__ __forceinline__ unsigned pk2(float a, float b) {
    return (unsigned)f2b(a) | ((unsigned)f2b(b) << 16);
}
__device__ __forceinline__ float logsig(float x) {
    return fminf(x, 0.f) - log1pf(expf(-fabsf(x)));
}
__device__ __forceinline__ void onmerge(float& m, float& s, float om, float os) {
    float nm = fmaxf(m, om);
    s = s * __expf(m - nm) + os * __expf(om - nm);
    m = nm;
}
// async global->LDS, 16B per lane; lds dest wave-uniform base (+lane*16 implicit)
__device__ __forceinline__ void gl_lds16(const u16* g, u16* l) {
    __builtin_amdgcn_global_load_lds(
        (const __attribute__((address_space(1))) unsigned*)(const void*)g,
        (__attribute__((address_space(3))) unsigned*)(void*)l, 16, 0, 0);
}

// ===================== cooperative megakernel =====================
// phase1 proj -> gsync -> phase2 sim -> gsync -> phase3 red -> gsync -> phase4 final
// Shared: buf 18432 u16 (36864B) + redf 4096B = 40960B -> exactly 4 blocks/CU.
__global__ __launch_bounds__(256, 4) void k_mega(
        const float* __restrict__ desc, const int* __restrict__ mask,
        const float* __restrict__ W, const float* __restrict__ bias,
        const float* __restrict__ mw, const float* __restrict__ mb,
        u16* __restrict__ out, float* __restrict__ wsf,
        u16* __restrict__ mdesc, u16* __restrict__ simw) {
    cg::grid_group gg = cg::this_grid();
    __shared__ __align__(16) u16 buf[18432];
    __shared__ float redf[128][8];   // sim: [r][0..1]=rpm [2..3]=rps [4..5]=cpm [6..7]=cps
    const int G = gridDim.x;
    int tid = threadIdx.x;
    int w = tid >> 6, lane = tid & 63;
    int ln = lane & 15, q = lane >> 4;
    int wr0 = (w >> 1) * 64, wc0 = (w & 1) * 64;
    int rsub = lane >> 3;                        // row-within-8 of lane's 16B
    int scol = (((lane & 7) ^ rsub) << 3);       // pre-swizzled global col (bf16)
    f32x4 zero = {0.f, 0.f, 0.f, 0.f};

    // ---------------- phase 1: projection GEMM (R4 fused-f32 body) ----------------
    for (int tt = blockIdx.x; tt < 512; tt += G) {
        int r0 = (tt & 255) * 128, c0 = (tt >> 8) * 128;
        int domatch = (tt < 256);
        u16* As = buf;
        u16* Bs = buf + 128 * LDA;
        f32x4 acc[4][4];
        #pragma unroll
        for (int a = 0; a < 4; ++a)
            #pragma unroll
            for (int b = 0; b < 4; ++b) acc[a][b] = zero;
        float mdot[4] = {0.f, 0.f, 0.f, 0.f};
        for (int kb = 0; kb < D; kb += 64) {
            __syncthreads();
            #pragma unroll
            for (int t = 0; t < 4; ++t) {
                int c = t * 256 + tid;          // chunk (8 bf16 each)
                int row = c >> 3, part = c & 7;
                const float* ap = desc + (size_t)(r0 + row) * D + kb + part * 8;
                float4 f0 = *(const float4*)ap;
                float4 f1 = *(const float4*)(ap + 4);
                uint4 va;
                va.x = pk2(f0.x, f0.y); va.y = pk2(f0.z, f0.w);
                va.z = pk2(f1.x, f1.y); va.w = pk2(f1.z, f1.w);
                *(uint4*)&As[row * LDA + part * 8] = va;
                if (domatch) {
                    float4 w0 = *(const float4*)(mw + kb + part * 8);
                    float4 w1 = *(const float4*)(mw + kb + part * 8 + 4);
                    mdot[t] += f0.x*w0.x + f0.y*w0.y + f0.z*w0.z + f0.w*w0.w
                             + f1.x*w1.x + f1.y*w1.y + f1.z*w1.z + f1.w*w1.w;
                }
                const float* bp = W + (size_t)(c0 + row) * D + kb + part * 8;
                float4 g0 = *(const float4*)bp;
                float4 g1 = *(const float4*)(bp + 4);
                uint4 vb;
                vb.x = pk2(g0.x, g0.y); vb.y = pk2(g0.z, g0.w);
                vb.z = pk2(g1.x, g1.y); vb.w = pk2(g1.z, g1.w);
                *(uint4*)&Bs[row * LDA + part * 8] = vb;
            }
            __syncthreads();
            #pragma unroll
            for (int kk = 0; kk < 64; kk += 32) {
                bf16x8 af[4], bfr[4];
                #pragma unroll
                for (int ri = 0; ri < 4; ++ri)
                    af[ri] = *(const bf16x8*)&As[(wr0 + ri*16 + ln) * LDA + kk + q*8];
                #pragma unroll
                for (int ci = 0; ci < 4; ++ci)
                    bfr[ci] = *(const bf16x8*)&Bs[(wc0 + ci*16 + ln) * LDA + kk + q*8];
                #pragma unroll
                for (int ri = 0; ri < 4; ++ri)
                    #pragma unroll
                    for (int ci = 0; ci < 4; ++ci)
                        acc[ri][ci] = __builtin_amdgcn_mfma_f32_16x16x32_bf16(af[ri], bfr[ci], acc[ri][ci], 0, 0, 0);
            }
        }
        if (domatch) {
            #pragma unroll
            for (int t = 0; t < 4; ++t) {
                float s = mdot[t];
                s += __shfl_xor(s, 1, 64);
                s += __shfl_xor(s, 2, 64);
                s += __shfl_xor(s, 4, 64);
                if ((tid & 7) == 0) {
                    int row_g = r0 + t * 32 + (tid >> 3);
                    float m = s + mb[0];
                    int b = row_g >> 11;
                    int i = row_g & (N - 1);
                    int pp = b >> 1, sid = b & 1;
                    float ls = logsig(m), lsn = logsig(-m);
                    if (sid == 0) { wsf[WS_LS0 + pp*N + i] = ls; wsf[WS_LSN0 + pp*N + i] = lsn; }
                    else          { wsf[WS_LS1 + pp*N + i] = ls; wsf[WS_LSN1 + pp*N + i] = lsn; }
                }
            }
        }
        // epilogue: stage tile in buf (tiles dead) -> uint4 stores
        __syncthreads();
        float bs[4];
        #pragma unroll
        for (int ci = 0; ci < 4; ++ci) bs[ci] = bias[c0 + wc0 + ci*16 + ln];
        #pragma unroll
        for (int ri = 0; ri < 4; ++ri) {
            #pragma unroll
            for (int reg = 0; reg < 4; ++reg) {
                int row_l = wr0 + ri*16 + q*4 + reg;
                #pragma unroll
                for (int ci = 0; ci < 4; ++ci) {
                    float v = (acc[ri][ci][reg] + bs[ci]) * 0.25f;
                    buf[row_l * LDST + wc0 + ci*16 + ln] = f2b(v);
                }
            }
        }
        __syncthreads();
        {
            int row_l = tid >> 1, half = tid & 1;
            u16* dp = mdesc + (size_t)(r0 + row_l) * D + c0 + half * 64;
            const u16* lp = &buf[row_l * LDST + half * 64];
            #pragma unroll
            for (int i = 0; i < 8; ++i)
                *(uint4*)(dp + i * 8) = *(const uint4*)(lp + i * 8);
        }
        __syncthreads();     // protect buf before next tile (only if G<512)
    }
    gg.sync();

    // ---------------- phase 2: similarity GEMM (R5 single-buf body) ----------------
    for (int tt = blockIdx.x; tt < 2048; tt += G) {
        int p = tt >> 8;
        int bx = (tt >> 4) & 15, by = tt & 15;
        int r0 = bx * 128, c0 = by * 128;
        const u16* Am = mdesc + (size_t)(2*p) * N * D;
        const u16* Bm = mdesc + (size_t)(2*p + 1) * N * D;
        u16* At = buf;           // [128*64] linear, gload_lds dest
        u16* Bt = buf + 8192;
        f32x4 acc[4][4];
        #pragma unroll
        for (int a = 0; a < 4; ++a)
            #pragma unroll
            for (int b = 0; b < 4; ++b) acc[a][b] = zero;
        for (int kb = 0; kb < D; kb += 64) {
            #pragma unroll
            for (int j = 0; j < 4; ++j) {
                int row = w * 32 + j * 8 + rsub;
                gl_lds16(Am + (size_t)(r0 + row) * D + kb + scol, At + (w * 32 + j * 8) * 64);
                gl_lds16(Bm + (size_t)(c0 + row) * D + kb + scol, Bt + (w * 32 + j * 8) * 64);
            }
            __syncthreads();   // drains vmcnt -> tiles complete
            #pragma unroll
            for (int kk = 0; kk < 64; kk += 32) {
                bf16x8 af[4], bfr[4];
                int cswz = (kk * 2 + q * 16) ^ ((ln & 7) << 4);
                #pragma unroll
                for (int ri = 0; ri < 4; ++ri)
                    af[ri] = *(const bf16x8*)((const char*)At + (wr0 + ri*16 + ln) * 128 + cswz);
                #pragma unroll
                for (int ci = 0; ci < 4; ++ci)
                    bfr[ci] = *(const bf16x8*)((const char*)Bt + (wc0 + ci*16 + ln) * 128 + cswz);
                #pragma unroll
                for (int ri = 0; ri < 4; ++ri)
                    #pragma unroll
                    for (int ci = 0; ci < 4; ++ci)
                        acc[ri][ci] = __builtin_amdgcn_mfma_f32_16x16x32_bf16(af[ri], bfr[ci], acc[ri][ci], 0, 0, 0);
            }
            __syncthreads();   // reads done before next-tile overwrite
        }
        const int* m0 = mask + (size_t)(2*p) * N;
        const int* m1 = mask + (size_t)(2*p + 1) * N;
        int mcol[4];
        #pragma unroll
        for (int ci = 0; ci < 4; ++ci) mcol[ci] = m1[c0 + wc0 + ci*16 + ln];
        #pragma unroll
        for (int ri = 0; ri < 4; ++ri) {
            #pragma unroll
            for (int reg = 0; reg < 4; ++reg) {
                int row_l = wr0 + ri*16 + q*4 + reg;
                int mr = m0[r0 + row_l];
                #pragma unroll
                for (int ci = 0; ci < 4; ++ci) {
                    float v = (mr && mcol[ci]) ? acc[ri][ci][reg] : MASKVAL;
                    acc[ri][ci][reg] = v;
                    buf[row_l * LDST + wc0 + ci*16 + ln] = f2b(v);
                }
            }
        }
        // row partials (two-pass)
        #pragma unroll
        for (int ri = 0; ri < 4; ++ri) {
            #pragma unroll
            for (int reg = 0; reg < 4; ++reg) {
                float x0 = acc[ri][0][reg], x1 = acc[ri][1][reg];
                float x2 = acc[ri][2][reg], x3 = acc[ri][3][reg];
                float m = fmaxf(fmaxf(x0, x1), fmaxf(x2, x3));
                #pragma unroll
                for (int off = 1; off <= 8; off <<= 1)
                    m = fmaxf(m, __shfl_xor(m, off, 64));
                float s = __expf(x0 - m) + __expf(x1 - m) + __expf(x2 - m) + __expf(x3 - m);
                #pragma unroll
                for (int off = 1; off <= 8; off <<= 1)
                    s += __shfl_xor(s, off, 64);
                if (ln == 0) {
                    int rl = wr0 + ri*16 + q*4 + reg;
                    redf[rl][w & 1] = m; redf[rl][2 + (w & 1)] = s;
                }
            }
        }
        // col partials (two-pass)
        #pragma unroll
        for (int ci = 0; ci < 4; ++ci) {
            float m = acc[0][ci][0];
            #pragma unroll
            for (int ri = 0; ri < 4; ++ri)
                #pragma unroll
                for (int reg = 0; reg < 4; ++reg)
                    if (!(ri == 0 && reg == 0)) m = fmaxf(m, acc[ri][ci][reg]);
            #pragma unroll
            for (int off = 16; off <= 32; off <<= 1)
                m = fmaxf(m, __shfl_xor(m, off, 64));
            float s = 0.f;
            #pragma unroll
            for (int ri = 0; ri < 4; ++ri)
                #pragma unroll
                for (int reg = 0; reg < 4; ++reg)
                    s += __expf(acc[ri][ci][reg] - m);
            #pragma unroll
            for (int off = 16; off <= 32; off <<= 1)
                s += __shfl_xor(s, off, 64);
            if (q == 0) {
                int cl = wc0 + ci*16 + ln;
                redf[cl][4 + (w >> 1)] = m; redf[cl][6 + (w >> 1)] = s;
            }
        }
        __syncthreads();
        {   // vectorized tile store to aligned scratch (stride N)
            int row_l = tid >> 1, half = tid & 1;
            u16* sp = simw + ((size_t)p * N + r0 + row_l) * N + c0 + half * 64;
            const u16* lp = &buf[row_l * LDST + half * 64];
            #pragma unroll
            for (int i = 0; i < 8; ++i)
                *(uint4*)(sp + i * 8) = *(const uint4*)(lp + i * 8);
        }
        if (tid < 128) {
            float m = redf[tid][0], s = redf[tid][2];
            onmerge(m, s, redf[tid][1], redf[tid][3]);
            size_t o = (size_t)(p * 16 + by) * N + r0 + tid;
            wsf[WS_RPM + o] = m; wsf[WS_RPS + o] = s;
        } else {
            int c = tid - 128;
            float m = redf[c][4], s = redf[c][6];
            onmerge(m, s, redf[c][5], redf[c][7]);
            size_t o = (size_t)(p * 16 + bx) * N + c0 + c;
            wsf[WS_CPM + o] = m;
            wsf[WS_CPS + o] = s;
        }
        __syncthreads();     // buf/redf reuse by next tile
    }
    gg.sync();

    // ---------------- phase 3: merge partials -> packed stats ----------------
    for (int u = blockIdx.x; u < 64; u += G) {
        int p = u >> 3;
        int i = (u & 7) * 256 + tid;
        float m = wsf[WS_CPM + (size_t)(p*16) * N + i];
        float s = wsf[WS_CPS + (size_t)(p*16) * N + i];
        #pragma unroll
        for (int rb = 1; rb < 16; ++rb)
            onmerge(m, s, wsf[WS_CPM + (size_t)(p*16 + rb) * N + i],
                          wsf[WS_CPS + (size_t)(p*16 + rb) * N + i]);
        float2 cpack;
        cpack.x = -m - logf(s);
        cpack.y = wsf[WS_LS1 + p*N + i];
        *(float2*)&wsf[WS_CST + ((size_t)p * N + i) * 2] = cpack;
        float rm = wsf[WS_RPM + (size_t)(p*16) * N + i];
        float rs = wsf[WS_RPS + (size_t)(p*16) * N + i];
        #pragma unroll
        for (int rb = 1; rb < 16; ++rb)
            onmerge(rm, rs, wsf[WS_RPM + (size_t)(p*16 + rb) * N + i],
                            wsf[WS_RPS + (size_t)(p*16 + rb) * N + i]);
        float4 rpack;
        rpack.x = -rm - logf(rs);
        rpack.y = wsf[WS_LS0  + p*N + i];
        rpack.z = wsf[WS_LSN0 + p*N + i];
        rpack.w = 0.f;
        *(float4*)&wsf[WS_ROW + ((size_t)p * N + i) * 4] = rpack;
    }
    gg.sync();

    // ---------------- phase 4: final assembly (R4 k_final v2 body) ----------------
    unsigned* up = (unsigned*)out;
    for (int u = blockIdx.x; u < PAIRS * 257; u += G) {
        int p = u / 257;
        int strip = u - p * 257;
        if (strip == 256) {          // border row i = N (no LDS use)
            int head = p & 1;
            size_t B0 = ((size_t)p * NO + N) * NO;
            size_t U0 = (B0 + head) >> 1;
            const float* lsn1 = wsf + WS_LSN1 + p * N;
            #pragma unroll
            for (int k = 0; k < 4; ++k) {
                int kk = k * 256 + tid;
                int j0 = head + 2 * kk;
                float o0 = (j0 < N) ? lsn1[j0] : 0.f;
                float o1 = (j0 + 1 < N) ? lsn1[j0 + 1] : 0.f;
                up[U0 + kk] = pk2(o0, o1);
            }
            if (tid == 0) {
                if (head) out[B0] = f2b(lsn1[0]);
                else      out[B0 + N] = 0;
            }
            continue;
        }
        int c8 = tid * 8;
        const float* cst = wsf + WS_CST + ((size_t)p * N + c8) * 2;
        float4 cs[4];
        #pragma unroll
        for (int k = 0; k < 4; ++k) cs[k] = *(const float4*)(cst + 4 * k);
        #pragma unroll
        for (int r = 0; r < 8; ++r) {
            int i = strip * 8 + r;
            int head = (p + i) & 1;
            float4 rsv = *(const float4*)&wsf[WS_ROW + ((size_t)p * N + i) * 4];
            float rc = rsv.x, l0 = rsv.y, ln0 = rsv.z;
            uint4 v = *(const uint4*)(simw + ((size_t)p * N + i) * N + c8);
            unsigned vv[4] = {v.x, v.y, v.z, v.w};
            float o[8];
            #pragma unroll
            for (int k = 0; k < 8; ++k) {
                float x = b2f((u16)(vv[k >> 1] >> ((k & 1) * 16)));
                float cA = ((const float*)&cs[0])[2 * k];
                float s1 = ((const float*)&cs[0])[2 * k + 1];
                float t = (x + rc) + (x + cA);
                o[k] = fmaxf(fmaxf(t, MASKVAL) + (l0 + s1), MASKVAL);
            }
            u16* stg = buf + r * 2052;        // [8][2052] view
            if (!head) {
                uint4 wv;
                wv.x = pk2(o[0], o[1]); wv.y = pk2(o[2], o[3]);
                wv.z = pk2(o[4], o[5]); wv.w = pk2(o[6], o[7]);
                *(uint4*)&stg[c8] = wv;
            } else {
                stg[c8 + 1] = f2b(o[0]);
                *(unsigned*)&stg[c8 + 2] = pk2(o[1], o[2]);
                *(unsigned*)&stg[c8 + 4] = pk2(o[3], o[4]);
                *(unsigned*)&stg[c8 + 6] = pk2(o[5], o[6]);
                stg[c8 + 8] = f2b(o[7]);
            }
            if (tid == 255) stg[2048 + head] = f2b(ln0);   // border col
        }
        __syncthreads();
        #pragma unroll
        for (int r = 0; r < 8; ++r) {
            int i = strip * 8 + r;
            int head = (p + i) & 1;
            size_t B0 = ((size_t)p * NO + i) * NO;
            size_t U0 = (B0 + head) >> 1;
            const unsigned* srow32 = (const unsigned*)(buf + r * 2052);
            #pragma unroll
            for (int k = 0; k < 4; ++k) {
                int kk = k * 256 + tid;
                up[U0 + kk] = srow32[kk + head];
            }
            if (tid == 0) {
                const u16* stg = buf + r * 2052;
                if (head) out[B0] = stg[1];        // out col 0
                else      out[B0 + N] = stg[2048]; // border col
            }
        }
        __syncthreads();     // stg reuse by next strip
    }
}

extern "C" void kernel_launch(void* const* d_in, const int* in_sizes, int n_in,
                              void* d_out, int out_size, void* d_ws, size_t ws_size,
                              hipStream_t stream) {
    const float* desc    = (const float*)d_in[0];
    const int*   mask    = (const int*)d_in[1];
    const float* proj_w  = (const float*)d_in[2];
    const float* proj_b  = (const float*)d_in[3];
    const float* match_w = (const float*)d_in[4];
    const float* match_b = (const float*)d_in[5];
    u16*   out = (u16*)d_out;
    float* wsf = (float*)d_ws;
    u16*   mdesc = (u16*)((char*)d_ws + (size_t)WS_F_COUNT * sizeof(float));
    u16*   simw  = mdesc + (size_t)16 * N * D;   // PAIRS*N*N bf16

    static int nb = 0;                 // blocks/CU, queried once (pure query: capture-safe)
    if (nb == 0) {
        if (hipOccupancyMaxActiveBlocksPerMultiprocessor(&nb, k_mega, 256, 0) != hipSuccess || nb < 1)
            nb = 1;
        if (nb > 4) nb = 4;
    }
    int grid = nb * 256;               // exact co-residency for cooperative launch

    void* args[10] = { (void*)&desc, (void*)&mask, (void*)&proj_w, (void*)&proj_b,
                       (void*)&match_w, (void*)&match_b, (void*)&out, (void*)&wsf,
                       (void*)&mdesc, (void*)&simw };
    hipLaunchCooperativeKernel((void*)k_mega, dim3(grid), dim3(256), args, 0, stream);
}

// Round 7
// 443.486 us; speedup vs baseline: 1.1257x; 1.1257x over previous
//
#include <hip/hip_runtime.h>
#include <hip/hip_cooperative_groups.h>
#include <math.h>

namespace cg = cooperative_groups;

typedef unsigned short u16;
typedef __attribute__((ext_vector_type(8))) short bf16x8;
typedef __attribute__((ext_vector_type(4))) float f32x4;

#define N 2048
#define D 256
#define PAIRS 8
#define NO 2049
#define MASKVAL -3.0e38f          // stored sentinel: finite in bf16
#define LDA 72                    // proj padded LDS row stride (u16), 144B (16B-mult)
#define LDST 136                  // epilogue stage row stride (u16), 16B-mult

// ws float region (float offsets within wsf) — layout as R4
#define WS_LS0   0
#define WS_LS1   (1*PAIRS*N)
#define WS_LSN0  (2*PAIRS*N)
#define WS_LSN1  (3*PAIRS*N)
#define WS_CST   (6*PAIRS*N)               // packed col stats {colA,s1} [PAIRS][N][2]
#define WS_RPM   (8*PAIRS*N)               // row partials max [PAIRS][16][N]
#define WS_RPS   (WS_RPM + PAIRS*16*N)
#define WS_CPM   (WS_RPS + PAIRS*16*N)     // col partials max [PAIRS][16][N]
#define WS_CPS   (WS_CPM + PAIRS*16*N)
#define WS_ROW   (WS_CPS + PAIRS*16*N)     // packed row stats {rc,l0,ln0,0} [PAIRS][N][4]
#define WS_F_COUNT (WS_ROW + 4*PAIRS*N)

__device__ __forceinline__ float b2f(u16 u) {
    return __uint_as_float(((unsigned)u) << 16);
}
__device__ __forceinline__ u16 f2b(float f) {  // RNE f32->bf16 (finite in)
    unsigned x = __float_as_uint(f);
    x += 0x7FFFu + ((x >> 16) & 1u);
    return (u16)(x >> 16);
}
__device__ __forceinline__ unsigned pk2(float a, float b) {
    return (unsigned)f2b(a) | ((unsigned)f2b(b) << 16);
}
__device__ __forceinline__ float logsig(float x) {
    return fminf(x, 0.f) - log1pf(expf(-fabsf(x)));
}
__device__ __forceinline__ void onmerge(float& m, float& s, float om, float os) {
    float nm = fmaxf(m, om);
    s = s * __expf(m - nm) + os * __expf(om - nm);
    m = nm;
}
// async global->LDS, 16B per lane; lds dest wave-uniform base (+lane*16 implicit)
__device__ __forceinline__ void gl_lds16(const u16* g, u16* l) {
    __builtin_amdgcn_global_load_lds(
        (const __attribute__((address_space(1))) unsigned*)(const void*)g,
        (__attribute__((address_space(3))) unsigned*)(void*)l, 16, 0, 0);
}

// ===================== cooperative megakernel v2 =====================
// Identical phase bodies to R6 (PASSED). Single fix: __launch_bounds__(256)
// WITHOUT the min-waves clause. R6's (256,4) budgeted 128 regs for the
// UNIFIED VGPR+AGPR file; acc[4][4] alone is 64 acc-regs, leaving 64 arch
// VGPRs -> scratch spills (measured: +140MB TCC traffic, MfmaUtil 1.6%).
// LDS 40960B still caps at 4 blocks/CU; occupancy query sizes the grid.
__global__ __launch_bounds__(256) void k_mega(
        const float* __restrict__ desc, const int* __restrict__ mask,
        const float* __restrict__ W, const float* __restrict__ bias,
        const float* __restrict__ mw, const float* __restrict__ mb,
        u16* __restrict__ out, float* __restrict__ wsf,
        u16* __restrict__ mdesc, u16* __restrict__ simw) {
    cg::grid_group gg = cg::this_grid();
    __shared__ __align__(16) u16 buf[18432];
    __shared__ float redf[128][8];   // sim: [r][0..1]=rpm [2..3]=rps [4..5]=cpm [6..7]=cps
    const int G = gridDim.x;
    int tid = threadIdx.x;
    int w = tid >> 6, lane = tid & 63;
    int ln = lane & 15, q = lane >> 4;
    int wr0 = (w >> 1) * 64, wc0 = (w & 1) * 64;
    int rsub = lane >> 3;                        // row-within-8 of lane's 16B
    int scol = (((lane & 7) ^ rsub) << 3);       // pre-swizzled global col (bf16)
    f32x4 zero = {0.f, 0.f, 0.f, 0.f};

    // ---------------- phase 1: projection GEMM (R4 fused-f32 body) ----------------
    for (int tt = blockIdx.x; tt < 512; tt += G) {
        int r0 = (tt & 255) * 128, c0 = (tt >> 8) * 128;
        int domatch = (tt < 256);
        u16* As = buf;
        u16* Bs = buf + 128 * LDA;
        f32x4 acc[4][4];
        #pragma unroll
        for (int a = 0; a < 4; ++a)
            #pragma unroll
            for (int b = 0; b < 4; ++b) acc[a][b] = zero;
        float mdot[4] = {0.f, 0.f, 0.f, 0.f};
        for (int kb = 0; kb < D; kb += 64) {
            __syncthreads();
            #pragma unroll
            for (int t = 0; t < 4; ++t) {
                int c = t * 256 + tid;          // chunk (8 bf16 each)
                int row = c >> 3, part = c & 7;
                const float* ap = desc + (size_t)(r0 + row) * D + kb + part * 8;
                float4 f0 = *(const float4*)ap;
                float4 f1 = *(const float4*)(ap + 4);
                uint4 va;
                va.x = pk2(f0.x, f0.y); va.y = pk2(f0.z, f0.w);
                va.z = pk2(f1.x, f1.y); va.w = pk2(f1.z, f1.w);
                *(uint4*)&As[row * LDA + part * 8] = va;
                if (domatch) {
                    float4 w0 = *(const float4*)(mw + kb + part * 8);
                    float4 w1 = *(const float4*)(mw + kb + part * 8 + 4);
                    mdot[t] += f0.x*w0.x + f0.y*w0.y + f0.z*w0.z + f0.w*w0.w
                             + f1.x*w1.x + f1.y*w1.y + f1.z*w1.z + f1.w*w1.w;
                }
                const float* bp = W + (size_t)(c0 + row) * D + kb + part * 8;
                float4 g0 = *(const float4*)bp;
                float4 g1 = *(const float4*)(bp + 4);
                uint4 vb;
                vb.x = pk2(g0.x, g0.y); vb.y = pk2(g0.z, g0.w);
                vb.z = pk2(g1.x, g1.y); vb.w = pk2(g1.z, g1.w);
                *(uint4*)&Bs[row * LDA + part * 8] = vb;
            }
            __syncthreads();
            #pragma unroll
            for (int kk = 0; kk < 64; kk += 32) {
                bf16x8 af[4], bfr[4];
                #pragma unroll
                for (int ri = 0; ri < 4; ++ri)
                    af[ri] = *(const bf16x8*)&As[(wr0 + ri*16 + ln) * LDA + kk + q*8];
                #pragma unroll
                for (int ci = 0; ci < 4; ++ci)
                    bfr[ci] = *(const bf16x8*)&Bs[(wc0 + ci*16 + ln) * LDA + kk + q*8];
                #pragma unroll
                for (int ri = 0; ri < 4; ++ri)
                    #pragma unroll
                    for (int ci = 0; ci < 4; ++ci)
                        acc[ri][ci] = __builtin_amdgcn_mfma_f32_16x16x32_bf16(af[ri], bfr[ci], acc[ri][ci], 0, 0, 0);
            }
        }
        if (domatch) {
            #pragma unroll
            for (int t = 0; t < 4; ++t) {
                float s = mdot[t];
                s += __shfl_xor(s, 1, 64);
                s += __shfl_xor(s, 2, 64);
                s += __shfl_xor(s, 4, 64);
                if ((tid & 7) == 0) {
                    int row_g = r0 + t * 32 + (tid >> 3);
                    float m = s + mb[0];
                    int b = row_g >> 11;
                    int i = row_g & (N - 1);
                    int pp = b >> 1, sid = b & 1;
                    float ls = logsig(m), lsn = logsig(-m);
                    if (sid == 0) { wsf[WS_LS0 + pp*N + i] = ls; wsf[WS_LSN0 + pp*N + i] = lsn; }
                    else          { wsf[WS_LS1 + pp*N + i] = ls; wsf[WS_LSN1 + pp*N + i] = lsn; }
                }
            }
        }
        // epilogue: stage tile in buf (tiles dead) -> uint4 stores
        __syncthreads();
        float bs[4];
        #pragma unroll
        for (int ci = 0; ci < 4; ++ci) bs[ci] = bias[c0 + wc0 + ci*16 + ln];
        #pragma unroll
        for (int ri = 0; ri < 4; ++ri) {
            #pragma unroll
            for (int reg = 0; reg < 4; ++reg) {
                int row_l = wr0 + ri*16 + q*4 + reg;
                #pragma unroll
                for (int ci = 0; ci < 4; ++ci) {
                    float v = (acc[ri][ci][reg] + bs[ci]) * 0.25f;
                    buf[row_l * LDST + wc0 + ci*16 + ln] = f2b(v);
                }
            }
        }
        __syncthreads();
        {
            int row_l = tid >> 1, half = tid & 1;
            u16* dp = mdesc + (size_t)(r0 + row_l) * D + c0 + half * 64;
            const u16* lp = &buf[row_l * LDST + half * 64];
            #pragma unroll
            for (int i = 0; i < 8; ++i)
                *(uint4*)(dp + i * 8) = *(const uint4*)(lp + i * 8);
        }
        __syncthreads();     // protect buf before next tile
    }
    gg.sync();

    // ---------------- phase 2: similarity GEMM (R5 single-buf body) ----------------
    for (int tt = blockIdx.x; tt < 2048; tt += G) {
        int p = tt >> 8;
        int bx = (tt >> 4) & 15, by = tt & 15;
        int r0 = bx * 128, c0 = by * 128;
        const u16* Am = mdesc + (size_t)(2*p) * N * D;
        const u16* Bm = mdesc + (size_t)(2*p + 1) * N * D;
        u16* At = buf;           // [128*64] linear, gload_lds dest
        u16* Bt = buf + 8192;
        f32x4 acc[4][4];
        #pragma unroll
        for (int a = 0; a < 4; ++a)
            #pragma unroll
            for (int b = 0; b < 4; ++b) acc[a][b] = zero;
        for (int kb = 0; kb < D; kb += 64) {
            #pragma unroll
            for (int j = 0; j < 4; ++j) {
                int row = w * 32 + j * 8 + rsub;
                gl_lds16(Am + (size_t)(r0 + row) * D + kb + scol, At + (w * 32 + j * 8) * 64);
                gl_lds16(Bm + (size_t)(c0 + row) * D + kb + scol, Bt + (w * 32 + j * 8) * 64);
            }
            __syncthreads();   // drains vmcnt -> tiles complete
            #pragma unroll
            for (int kk = 0; kk < 64; kk += 32) {
                bf16x8 af[4], bfr[4];
                int cswz = (kk * 2 + q * 16) ^ ((ln & 7) << 4);
                #pragma unroll
                for (int ri = 0; ri < 4; ++ri)
                    af[ri] = *(const bf16x8*)((const char*)At + (wr0 + ri*16 + ln) * 128 + cswz);
                #pragma unroll
                for (int ci = 0; ci < 4; ++ci)
                    bfr[ci] = *(const bf16x8*)((const char*)Bt + (wc0 + ci*16 + ln) * 128 + cswz);
                #pragma unroll
                for (int ri = 0; ri < 4; ++ri)
                    #pragma unroll
                    for (int ci = 0; ci < 4; ++ci)
                        acc[ri][ci] = __builtin_amdgcn_mfma_f32_16x16x32_bf16(af[ri], bfr[ci], acc[ri][ci], 0, 0, 0);
            }
            __syncthreads();   // reads done before next-tile overwrite
        }
        const int* m0 = mask + (size_t)(2*p) * N;
        const int* m1 = mask + (size_t)(2*p + 1) * N;
        int mcol[4];
        #pragma unroll
        for (int ci = 0; ci < 4; ++ci) mcol[ci] = m1[c0 + wc0 + ci*16 + ln];
        #pragma unroll
        for (int ri = 0; ri < 4; ++ri) {
            #pragma unroll
            for (int reg = 0; reg < 4; ++reg) {
                int row_l = wr0 + ri*16 + q*4 + reg;
                int mr = m0[r0 + row_l];
                #pragma unroll
                for (int ci = 0; ci < 4; ++ci) {
                    float v = (mr && mcol[ci]) ? acc[ri][ci][reg] : MASKVAL;
                    acc[ri][ci][reg] = v;
                    buf[row_l * LDST + wc0 + ci*16 + ln] = f2b(v);
                }
            }
        }
        // row partials (two-pass)
        #pragma unroll
        for (int ri = 0; ri < 4; ++ri) {
            #pragma unroll
            for (int reg = 0; reg < 4; ++reg) {
                float x0 = acc[ri][0][reg], x1 = acc[ri][1][reg];
                float x2 = acc[ri][2][reg], x3 = acc[ri][3][reg];
                float m = fmaxf(fmaxf(x0, x1), fmaxf(x2, x3));
                #pragma unroll
                for (int off = 1; off <= 8; off <<= 1)
                    m = fmaxf(m, __shfl_xor(m, off, 64));
                float s = __expf(x0 - m) + __expf(x1 - m) + __expf(x2 - m) + __expf(x3 - m);
                #pragma unroll
                for (int off = 1; off <= 8; off <<= 1)
                    s += __shfl_xor(s, off, 64);
                if (ln == 0) {
                    int rl = wr0 + ri*16 + q*4 + reg;
                    redf[rl][w & 1] = m; redf[rl][2 + (w & 1)] = s;
                }
            }
        }
        // col partials (two-pass)
        #pragma unroll
        for (int ci = 0; ci < 4; ++ci) {
            float m = acc[0][ci][0];
            #pragma unroll
            for (int ri = 0; ri < 4; ++ri)
                #pragma unroll
                for (int reg = 0; reg < 4; ++reg)
                    if (!(ri == 0 && reg == 0)) m = fmaxf(m, acc[ri][ci][reg]);
            #pragma unroll
            for (int off = 16; off <= 32; off <<= 1)
                m = fmaxf(m, __shfl_xor(m, off, 64));
            float s = 0.f;
            #pragma unroll
            for (int ri = 0; ri < 4; ++ri)
                #pragma unroll
                for (int reg = 0; reg < 4; ++reg)
                    s += __expf(acc[ri][ci][reg] - m);
            #pragma unroll
            for (int off = 16; off <= 32; off <<= 1)
                s += __shfl_xor(s, off, 64);
            if (q == 0) {
                int cl = wc0 + ci*16 + ln;
                redf[cl][4 + (w >> 1)] = m; redf[cl][6 + (w >> 1)] = s;
            }
        }
        __syncthreads();
        {   // vectorized tile store to aligned scratch (stride N)
            int row_l = tid >> 1, half = tid & 1;
            u16* sp = simw + ((size_t)p * N + r0 + row_l) * N + c0 + half * 64;
            const u16* lp = &buf[row_l * LDST + half * 64];
            #pragma unroll
            for (int i = 0; i < 8; ++i)
                *(uint4*)(sp + i * 8) = *(const uint4*)(lp + i * 8);
        }
        if (tid < 128) {
            float m = redf[tid][0], s = redf[tid][2];
            onmerge(m, s, redf[tid][1], redf[tid][3]);
            size_t o = (size_t)(p * 16 + by) * N + r0 + tid;
            wsf[WS_RPM + o] = m; wsf[WS_RPS + o] = s;
        } else {
            int c = tid - 128;
            float m = redf[c][4], s = redf[c][6];
            onmerge(m, s, redf[c][5], redf[c][7]);
            size_t o = (size_t)(p * 16 + bx) * N + c0 + c;
            wsf[WS_CPM + o] = m;
            wsf[WS_CPS + o] = s;
        }
        __syncthreads();     // buf/redf reuse by next tile
    }
    gg.sync();

    // ---------------- phase 3: merge partials -> packed stats ----------------
    for (int u = blockIdx.x; u < 64; u += G) {
        int p = u >> 3;
        int i = (u & 7) * 256 + tid;
        float m = wsf[WS_CPM + (size_t)(p*16) * N + i];
        float s = wsf[WS_CPS + (size_t)(p*16) * N + i];
        #pragma unroll
        for (int rb = 1; rb < 16; ++rb)
            onmerge(m, s, wsf[WS_CPM + (size_t)(p*16 + rb) * N + i],
                          wsf[WS_CPS + (size_t)(p*16 + rb) * N + i]);
        float2 cpack;
        cpack.x = -m - logf(s);
        cpack.y = wsf[WS_LS1 + p*N + i];
        *(float2*)&wsf[WS_CST + ((size_t)p * N + i) * 2] = cpack;
        float rm = wsf[WS_RPM + (size_t)(p*16) * N + i];
        float rs = wsf[WS_RPS + (size_t)(p*16) * N + i];
        #pragma unroll
        for (int rb = 1; rb < 16; ++rb)
            onmerge(rm, rs, wsf[WS_RPM + (size_t)(p*16 + rb) * N + i],
                            wsf[WS_RPS + (size_t)(p*16 + rb) * N + i]);
        float4 rpack;
        rpack.x = -rm - logf(rs);
        rpack.y = wsf[WS_LS0  + p*N + i];
        rpack.z = wsf[WS_LSN0 + p*N + i];
        rpack.w = 0.f;
        *(float4*)&wsf[WS_ROW + ((size_t)p * N + i) * 4] = rpack;
    }
    gg.sync();

    // ---------------- phase 4: final assembly (R4 k_final v2 body) ----------------
    unsigned* up = (unsigned*)out;
    for (int u = blockIdx.x; u < PAIRS * 257; u += G) {
        int p = u / 257;
        int strip = u - p * 257;
        if (strip == 256) {          // border row i = N (no LDS use)
            int head = p & 1;
            size_t B0 = ((size_t)p * NO + N) * NO;
            size_t U0 = (B0 + head) >> 1;
            const float* lsn1 = wsf + WS_LSN1 + p * N;
            #pragma unroll
            for (int k = 0; k < 4; ++k) {
                int kk = k * 256 + tid;
                int j0 = head + 2 * kk;
                float o0 = (j0 < N) ? lsn1[j0] : 0.f;
                float o1 = (j0 + 1 < N) ? lsn1[j0 + 1] : 0.f;
                up[U0 + kk] = pk2(o0, o1);
            }
            if (tid == 0) {
                if (head) out[B0] = f2b(lsn1[0]);
                else      out[B0 + N] = 0;
            }
            continue;
        }
        int c8 = tid * 8;
        const float* cst = wsf + WS_CST + ((size_t)p * N + c8) * 2;
        float4 cs[4];
        #pragma unroll
        for (int k = 0; k < 4; ++k) cs[k] = *(const float4*)(cst + 4 * k);
        #pragma unroll
        for (int r = 0; r < 8; ++r) {
            int i = strip * 8 + r;
            int head = (p + i) & 1;
            float4 rsv = *(const float4*)&wsf[WS_ROW + ((size_t)p * N + i) * 4];
            float rc = rsv.x, l0 = rsv.y, ln0 = rsv.z;
            uint4 v = *(const uint4*)(simw + ((size_t)p * N + i) * N + c8);
            unsigned vv[4] = {v.x, v.y, v.z, v.w};
            float o[8];
            #pragma unroll
            for (int k = 0; k < 8; ++k) {
                float x = b2f((u16)(vv[k >> 1] >> ((k & 1) * 16)));
                float cA = ((const float*)&cs[0])[2 * k];
                float s1 = ((const float*)&cs[0])[2 * k + 1];
                float t = (x + rc) + (x + cA);
                o[k] = fmaxf(fmaxf(t, MASKVAL) + (l0 + s1), MASKVAL);
            }
            u16* stg = buf + r * 2052;        // [8][2052] view
            if (!head) {
                uint4 wv;
                wv.x = pk2(o[0], o[1]); wv.y = pk2(o[2], o[3]);
                wv.z = pk2(o[4], o[5]); wv.w = pk2(o[6], o[7]);
                *(uint4*)&stg[c8] = wv;
            } else {
                stg[c8 + 1] = f2b(o[0]);
                *(unsigned*)&stg[c8 + 2] = pk2(o[1], o[2]);
                *(unsigned*)&stg[c8 + 4] = pk2(o[3], o[4]);
                *(unsigned*)&stg[c8 + 6] = pk2(o[5], o[6]);
                stg[c8 + 8] = f2b(o[7]);
            }
            if (tid == 255) stg[2048 + head] = f2b(ln0);   // border col
        }
        __syncthreads();
        #pragma unroll
        for (int r = 0; r < 8; ++r) {
            int i = strip * 8 + r;
            int head = (p + i) & 1;
            size_t B0 = ((size_t)p * NO + i) * NO;
            size_t U0 = (B0 + head) >> 1;
            const unsigned* srow32 = (const unsigned*)(buf + r * 2052);
            #pragma unroll
            for (int k = 0; k < 4; ++k) {
                int kk = k * 256 + tid;
                up[U0 + kk] = srow32[kk + head];
            }
            if (tid == 0) {
                const u16* stg = buf + r * 2052;
                if (head) out[B0] = stg[1];        // out col 0
                else      out[B0 + N] = stg[2048]; // border col
            }
        }
        __syncthreads();     // stg reuse by next strip
    }
}

extern "C" void kernel_launch(void* const* d_in, const int* in_sizes, int n_in,
                              void* d_out, int out_size, void* d_ws, size_t ws_size,
                              hipStream_t stream) {
    const float* desc    = (const float*)d_in[0];
    const int*   mask    = (const int*)d_in[1];
    const float* proj_w  = (const float*)d_in[2];
    const float* proj_b  = (const float*)d_in[3];
    const float* match_w = (const float*)d_in[4];
    const float* match_b = (const float*)d_in[5];
    u16*   out = (u16*)d_out;
    float* wsf = (float*)d_ws;
    u16*   mdesc = (u16*)((char*)d_ws + (size_t)WS_F_COUNT * sizeof(float));
    u16*   simw  = mdesc + (size_t)16 * N * D;   // PAIRS*N*N bf16

    static int nb = 0;                 // blocks/CU, queried once (pure query: capture-safe)
    if (nb == 0) {
        if (hipOccupancyMaxActiveBlocksPerMultiprocessor(&nb, k_mega, 256, 0) != hipSuccess || nb < 1)
            nb = 1;
        if (nb > 4) nb = 4;
    }
    int grid = nb * 256;               // exact co-residency for cooperative launch

    void* args[10] = { (void*)&desc, (void*)&mask, (void*)&proj_w, (void*)&proj_b,
                       (void*)&match_w, (void*)&match_b, (void*)&out, (void*)&wsf,
                       (void*)&mdesc, (void*)&simw };
    hipLaunchCooperativeKernel((void*)k_mega, dim3(grid), dim3(256), args, 0, stream);
}

// Round 8
// 250.478 us; speedup vs baseline: 1.9931x; 1.7706x over previous
//
#include <hip/hip_runtime.h>
#include <math.h>

typedef unsigned short u16;
typedef __attribute__((ext_vector_type(8))) short bf16x8;
typedef __attribute__((ext_vector_type(4))) float f32x4;

#define N 2048
#define D 256
#define PAIRS 8
#define NO 2049
#define MASKVAL -3.0e38f          // stored sentinel: finite in bf16
#define LDA 72                    // proj padded LDS row stride (u16)
#define LDST 136                  // epilogue stage row stride (u16), 16B-mult

// ws float region (float offsets within wsf)
#define WS_LS0   0
#define WS_LS1   (1*PAIRS*N)
#define WS_LSN0  (2*PAIRS*N)
#define WS_LSN1  (3*PAIRS*N)
#define WS_CST   (6*PAIRS*N)               // packed col stats {colA,s1} [PAIRS][N][2]
#define WS_RPM   (8*PAIRS*N)               // row partials max [PAIRS][16][N]
#define WS_RPS   (WS_RPM + PAIRS*16*N)
#define WS_CPM   (WS_RPS + PAIRS*16*N)     // col partials max [PAIRS][16][N]
#define WS_CPS   (WS_CPM + PAIRS*16*N)
#define WS_ROW   (WS_CPS + PAIRS*16*N)     // packed row stats {rc,l0,ln0,0} [PAIRS][N][4]
#define WS_F_COUNT (WS_ROW + 4*PAIRS*N)

__device__ __forceinline__ float b2f(u16 u) {
    return __uint_as_float(((unsigned)u) << 16);
}
__device__ __forceinline__ u16 f2b(float f) {  // RNE f32->bf16 (finite in)
    unsigned x = __float_as_uint(f);
    x += 0x7FFFu + ((x >> 16) & 1u);
    return (u16)(x >> 16);
}
__device__ __forceinline__ unsigned pk2(float a, float b) {
    return (unsigned)f2b(a) | ((unsigned)f2b(b) << 16);
}
__device__ __forceinline__ float logsig(float x) {
    return fminf(x, 0.f) - log1pf(expf(-fabsf(x)));
}
__device__ __forceinline__ void onmerge(float& m, float& s, float om, float os) {
    float nm = fmaxf(m, om);
    s = s * __expf(m - nm) + os * __expf(om - nm);
    m = nm;
}
// async global->LDS, 16B per lane; lds dest wave-uniform base (+lane*16 implicit)
__device__ __forceinline__ void gl_lds16(const u16* g, u16* l) {
    __builtin_amdgcn_global_load_lds(
        (const __attribute__((address_space(1))) unsigned*)(const void*)g,
        (__attribute__((address_space(3))) unsigned*)(void*)l, 16, 0, 0);
}

// ---- projection GEMM via MFMA + fused matchability (R4 body) ----
__global__ __launch_bounds__(256) void k_proj_mfma(const float* __restrict__ A,
                                                   const float* __restrict__ W,
                                                   const float* __restrict__ bias,
                                                   const float* __restrict__ mw,
                                                   const float* __restrict__ mb,
                                                   u16* __restrict__ mdesc,
                                                   float* __restrict__ wsf) {
    __shared__ union {
        struct { u16 A[128 * LDA]; u16 B[128 * LDA]; } t;
        u16 stage[128][LDST];
    } sh;
    int r0 = blockIdx.x * 128, c0 = blockIdx.y * 128;
    int tid = threadIdx.x;
    int w = tid >> 6, lane = tid & 63;
    int ln = lane & 15, q = lane >> 4;
    int wr0 = (w >> 1) * 64, wc0 = (w & 1) * 64;
    f32x4 zero = {0.f, 0.f, 0.f, 0.f};
    f32x4 acc[4][4];
    #pragma unroll
    for (int a = 0; a < 4; ++a)
        #pragma unroll
        for (int b = 0; b < 4; ++b) acc[a][b] = zero;
    float mdot[4] = {0.f, 0.f, 0.f, 0.f};
    int domatch = (blockIdx.y == 0);

    for (int kb = 0; kb < D; kb += 64) {
        __syncthreads();
        #pragma unroll
        for (int t = 0; t < 4; ++t) {
            int c = t * 256 + tid;          // chunk (8 bf16 each)
            int row = c >> 3, part = c & 7;
            const float* ap = A + (size_t)(r0 + row) * D + kb + part * 8;
            float4 f0 = *(const float4*)ap;
            float4 f1 = *(const float4*)(ap + 4);
            uint4 va;
            va.x = pk2(f0.x, f0.y); va.y = pk2(f0.z, f0.w);
            va.z = pk2(f1.x, f1.y); va.w = pk2(f1.z, f1.w);
            *(uint4*)&sh.t.A[row * LDA + part * 8] = va;
            if (domatch) {
                float4 w0 = *(const float4*)(mw + kb + part * 8);
                float4 w1 = *(const float4*)(mw + kb + part * 8 + 4);
                mdot[t] += f0.x*w0.x + f0.y*w0.y + f0.z*w0.z + f0.w*w0.w
                         + f1.x*w1.x + f1.y*w1.y + f1.z*w1.z + f1.w*w1.w;
            }
            const float* bp = W + (size_t)(c0 + row) * D + kb + part * 8;
            float4 g0 = *(const float4*)bp;
            float4 g1 = *(const float4*)(bp + 4);
            uint4 vb;
            vb.x = pk2(g0.x, g0.y); vb.y = pk2(g0.z, g0.w);
            vb.z = pk2(g1.x, g1.y); vb.w = pk2(g1.z, g1.w);
            *(uint4*)&sh.t.B[row * LDA + part * 8] = vb;
        }
        __syncthreads();
        #pragma unroll
        for (int kk = 0; kk < 64; kk += 32) {
            bf16x8 af[4], bf[4];
            #pragma unroll
            for (int ri = 0; ri < 4; ++ri)
                af[ri] = *(const bf16x8*)&sh.t.A[(wr0 + ri*16 + ln) * LDA + kk + q*8];
            #pragma unroll
            for (int ci = 0; ci < 4; ++ci)
                bf[ci] = *(const bf16x8*)&sh.t.B[(wc0 + ci*16 + ln) * LDA + kk + q*8];
            #pragma unroll
            for (int ri = 0; ri < 4; ++ri)
                #pragma unroll
                for (int ci = 0; ci < 4; ++ci)
                    acc[ri][ci] = __builtin_amdgcn_mfma_f32_16x16x32_bf16(af[ri], bf[ci], acc[ri][ci], 0, 0, 0);
        }
    }
    if (domatch) {
        #pragma unroll
        for (int t = 0; t < 4; ++t) {
            float s = mdot[t];
            s += __shfl_xor(s, 1, 64);
            s += __shfl_xor(s, 2, 64);
            s += __shfl_xor(s, 4, 64);
            if ((tid & 7) == 0) {
                int row_g = r0 + t * 32 + (tid >> 3);
                float m = s + mb[0];
                int b = row_g >> 11;
                int i = row_g & (N - 1);
                int pp = b >> 1, sid = b & 1;
                float ls = logsig(m), lsn = logsig(-m);
                if (sid == 0) { wsf[WS_LS0 + pp*N + i] = ls; wsf[WS_LSN0 + pp*N + i] = lsn; }
                else          { wsf[WS_LS1 + pp*N + i] = ls; wsf[WS_LSN1 + pp*N + i] = lsn; }
            }
        }
    }
    // epilogue: stage tile in LDS (union with A/B, dead now) -> vector stores
    __syncthreads();   // all waves done reading t.A/t.B
    float bs[4];
    #pragma unroll
    for (int ci = 0; ci < 4; ++ci) bs[ci] = bias[c0 + wc0 + ci*16 + ln];
    #pragma unroll
    for (int ri = 0; ri < 4; ++ri) {
        #pragma unroll
        for (int reg = 0; reg < 4; ++reg) {
            int row_l = wr0 + ri*16 + q*4 + reg;
            #pragma unroll
            for (int ci = 0; ci < 4; ++ci) {
                float v = (acc[ri][ci][reg] + bs[ci]) * 0.25f;
                sh.stage[row_l][wc0 + ci*16 + ln] = f2b(v);
            }
        }
    }
    __syncthreads();
    {
        int row_l = tid >> 1, half = tid & 1;
        u16* dp = mdesc + (size_t)(r0 + row_l) * D + c0 + half * 64;
        const u16* lp = &sh.stage[row_l][half * 64];
        #pragma unroll
        for (int i = 0; i < 8; ++i)
            *(uint4*)(dp + i * 8) = *(const uint4*)(lp + i * 8);
    }
}

// ---- similarity GEMM via MFMA (single-buffered R2/R5 structure) ----
// LDS tiles linear [128][64] u16 (gload_lds dest), XOR-swizzle via pre-swizzled
// GLOBAL source (chunk ^= row&7) + swizzled fragment-read byte offset.
__global__ __launch_bounds__(256) void k_sim_mfma(const u16* __restrict__ mdesc,
                                                  const int* __restrict__ mask,
                                                  u16* __restrict__ sim,
                                                  float* __restrict__ wsf) {
    __shared__ union {
        struct { u16 A[128 * 64]; u16 B[128 * 64]; } t;   // linear, gload_lds dest
        u16 stage[128][LDST];
    } sh;
    __shared__ float rpm[128][2], rps[128][2];
    __shared__ float cpm[128][2], cps[128][2];
    int p = blockIdx.z;
    const u16* Am = mdesc + (size_t)(2*p) * N * D;
    const u16* Bm = mdesc + (size_t)(2*p + 1) * N * D;
    int r0 = blockIdx.x * 128, c0 = blockIdx.y * 128;
    int tid = threadIdx.x;
    int w = tid >> 6, lane = tid & 63;
    int ln = lane & 15, q = lane >> 4;
    int wr0 = (w >> 1) * 64, wc0 = (w & 1) * 64;
    int rsub = lane >> 3;                        // row-within-8 of this lane's 16B
    int scol = (((lane & 7) ^ rsub) << 3);       // pre-swizzled global col (bf16)
    f32x4 zero = {0.f, 0.f, 0.f, 0.f};
    f32x4 acc[4][4];
    #pragma unroll
    for (int a = 0; a < 4; ++a)
        #pragma unroll
        for (int b = 0; b < 4; ++b) acc[a][b] = zero;

    for (int kb = 0; kb < D; kb += 64) {
        #pragma unroll
        for (int j = 0; j < 4; ++j) {
            int row = w * 32 + j * 8 + rsub;
            gl_lds16(Am + (size_t)(r0 + row) * D + kb + scol, &sh.t.A[(w * 32 + j * 8) * 64]);
            gl_lds16(Bm + (size_t)(c0 + row) * D + kb + scol, &sh.t.B[(w * 32 + j * 8) * 64]);
        }
        __syncthreads();   // drains vmcnt -> LDS tiles complete
        #pragma unroll
        for (int kk = 0; kk < 64; kk += 32) {
            bf16x8 af[4], bf[4];
            int cswz = (kk * 2 + q * 16) ^ ((ln & 7) << 4);   // row&7 == ln&7
            #pragma unroll
            for (int ri = 0; ri < 4; ++ri)
                af[ri] = *(const bf16x8*)((const char*)sh.t.A + (wr0 + ri*16 + ln) * 128 + cswz);
            #pragma unroll
            for (int ci = 0; ci < 4; ++ci)
                bf[ci] = *(const bf16x8*)((const char*)sh.t.B + (wc0 + ci*16 + ln) * 128 + cswz);
            #pragma unroll
            for (int ri = 0; ri < 4; ++ri)
                #pragma unroll
                for (int ci = 0; ci < 4; ++ci)
                    acc[ri][ci] = __builtin_amdgcn_mfma_f32_16x16x32_bf16(af[ri], bf[ci], acc[ri][ci], 0, 0, 0);
        }
        __syncthreads();   // reads done before next-tile overwrite
    }
    const int* m0 = mask + (size_t)(2*p) * N;
    const int* m1 = mask + (size_t)(2*p + 1) * N;
    int mcol[4];
    #pragma unroll
    for (int ci = 0; ci < 4; ++ci) mcol[ci] = m1[c0 + wc0 + ci*16 + ln];
    // apply mask in place + stage bf16 tile in LDS (t.A/t.B dead after last sync)
    #pragma unroll
    for (int ri = 0; ri < 4; ++ri) {
        #pragma unroll
        for (int reg = 0; reg < 4; ++reg) {
            int row_l = wr0 + ri*16 + q*4 + reg;
            int mr = m0[r0 + row_l];
            #pragma unroll
            for (int ci = 0; ci < 4; ++ci) {
                float v = (mr && mcol[ci]) ? acc[ri][ci][reg] : MASKVAL;
                acc[ri][ci][reg] = v;
                sh.stage[row_l][wc0 + ci*16 + ln] = f2b(v);
            }
        }
    }
    // row partials, two-pass: max over 64 cols, then sum of exp(x - max)
    #pragma unroll
    for (int ri = 0; ri < 4; ++ri) {
        #pragma unroll
        for (int reg = 0; reg < 4; ++reg) {
            float x0 = acc[ri][0][reg], x1 = acc[ri][1][reg];
            float x2 = acc[ri][2][reg], x3 = acc[ri][3][reg];
            float m = fmaxf(fmaxf(x0, x1), fmaxf(x2, x3));
            #pragma unroll
            for (int off = 1; off <= 8; off <<= 1)
                m = fmaxf(m, __shfl_xor(m, off, 64));
            float s = __expf(x0 - m) + __expf(x1 - m) + __expf(x2 - m) + __expf(x3 - m);
            #pragma unroll
            for (int off = 1; off <= 8; off <<= 1)
                s += __shfl_xor(s, off, 64);
            if (ln == 0) {
                int rl = wr0 + ri*16 + q*4 + reg;
                rpm[rl][w & 1] = m; rps[rl][w & 1] = s;
            }
        }
    }
    // col partials, two-pass: max over 64 rows, then sum of exp(x - max)
    #pragma unroll
    for (int ci = 0; ci < 4; ++ci) {
        float m = acc[0][ci][0];
        #pragma unroll
        for (int ri = 0; ri < 4; ++ri)
            #pragma unroll
            for (int reg = 0; reg < 4; ++reg)
                if (!(ri == 0 && reg == 0)) m = fmaxf(m, acc[ri][ci][reg]);
        #pragma unroll
        for (int off = 16; off <= 32; off <<= 1)
            m = fmaxf(m, __shfl_xor(m, off, 64));
        float s = 0.f;
        #pragma unroll
        for (int ri = 0; ri < 4; ++ri)
            #pragma unroll
            for (int reg = 0; reg < 4; ++reg)
                s += __expf(acc[ri][ci][reg] - m);
        #pragma unroll
        for (int off = 16; off <= 32; off <<= 1)
            s += __shfl_xor(s, off, 64);
        if (q == 0) {
            int cl = wc0 + ci*16 + ln;
            cpm[cl][w >> 1] = m; cps[cl][w >> 1] = s;
        }
    }
    __syncthreads();
    // vectorized tile store to aligned scratch (stride N)
    {
        int row_l = tid >> 1, half = tid & 1;
        u16* sp = sim + ((size_t)p * N + r0 + row_l) * N + c0 + half * 64;
        const u16* lp = &sh.stage[row_l][half * 64];
        #pragma unroll
        for (int i = 0; i < 8; ++i)
            *(uint4*)(sp + i * 8) = *(const uint4*)(lp + i * 8);
    }
    if (tid < 128) {
        float m = rpm[tid][0], s = rps[tid][0];
        onmerge(m, s, rpm[tid][1], rps[tid][1]);
        size_t o = (size_t)(p * 16 + blockIdx.y) * N + r0 + tid;
        wsf[WS_RPM + o] = m; wsf[WS_RPS + o] = s;
    } else {
        int c = tid - 128;
        float m = cpm[c][0], s = cps[c][0];
        onmerge(m, s, cpm[c][1], cps[c][1]);
        size_t o = (size_t)(p * 16 + blockIdx.x) * N + c0 + c;
        wsf[WS_CPM + o] = m;
        wsf[WS_CPS + o] = s;
    }
}

// ---- merge 16 chunk partials -> packed final stats (rows AND cols) ----
__global__ __launch_bounds__(256) void k_red(float* __restrict__ wsf) {
    int i = blockIdx.x * 256 + threadIdx.x;
    int p = blockIdx.y;
    // columns -> {colA = -cmax - log(csum), s1}
    float m = wsf[WS_CPM + (size_t)(p*16) * N + i];
    float s = wsf[WS_CPS + (size_t)(p*16) * N + i];
    #pragma unroll
    for (int rb = 1; rb < 16; ++rb)
        onmerge(m, s, wsf[WS_CPM + (size_t)(p*16 + rb) * N + i],
                      wsf[WS_CPS + (size_t)(p*16 + rb) * N + i]);
    float2 cpack;
    cpack.x = -m - logf(s);
    cpack.y = wsf[WS_LS1 + p*N + i];
    *(float2*)&wsf[WS_CST + ((size_t)p * N + i) * 2] = cpack;
    // rows -> {rc = -rmax - log(rsum), l0, ln0, 0}
    float rm = wsf[WS_RPM + (size_t)(p*16) * N + i];
    float rs = wsf[WS_RPS + (size_t)(p*16) * N + i];
    #pragma unroll
    for (int rb = 1; rb < 16; ++rb)
        onmerge(rm, rs, wsf[WS_RPM + (size_t)(p*16 + rb) * N + i],
                        wsf[WS_RPS + (size_t)(p*16 + rb) * N + i]);
    float4 rpack;
    rpack.x = -rm - logf(rs);
    rpack.y = wsf[WS_LS0  + p*N + i];
    rpack.z = wsf[WS_LSN0 + p*N + i];
    rpack.w = 0.f;
    *(float4*)&wsf[WS_ROW + ((size_t)p * N + i) * 4] = rpack;
}

// ---- final v2: 8 rows/block; uint4 sim loads, packed stats, LDS-shifted
//      stores so all `out` writes are aligned coalesced uints ----
__global__ __launch_bounds__(256) void k_final(u16* __restrict__ out,
                                               const u16* __restrict__ sim,
                                               const float* __restrict__ wsf) {
    int strip = blockIdx.x;     // rows 8*strip .. 8*strip+7; strip 256 = border
    int p = blockIdx.y;
    int tid = threadIdx.x;
    unsigned* up = (unsigned*)out;
    if (strip == 256) {          // border row i = N
        int head = p & 1;        // (p + 2048) & 1
        size_t B0 = ((size_t)p * NO + N) * NO;
        size_t U0 = (B0 + head) >> 1;
        const float* lsn1 = wsf + WS_LSN1 + p * N;
        #pragma unroll
        for (int k = 0; k < 4; ++k) {
            int kk = k * 256 + tid;
            int j0 = head + 2 * kk;
            float o0 = (j0 < N) ? lsn1[j0] : 0.f;
            float o1 = (j0 + 1 < N) ? lsn1[j0 + 1] : 0.f;
            up[U0 + kk] = pk2(o0, o1);
        }
        if (tid == 0) {
            if (head) out[B0] = f2b(lsn1[0]);
            else      out[B0 + N] = 0;
        }
        return;
    }
    __shared__ u16 stg[8][2052];   // slot j+head holds out col j; +border slot
    int c8 = tid * 8;
    // packed col stats for this thread's 8 cols: {colA, s1} pairs, 64B
    const float* cst = wsf + WS_CST + ((size_t)p * N + c8) * 2;
    float4 cs[4];
    #pragma unroll
    for (int k = 0; k < 4; ++k) cs[k] = *(const float4*)(cst + 4 * k);
    #pragma unroll
    for (int r = 0; r < 8; ++r) {
        int i = strip * 8 + r;
        int head = (p + i) & 1;
        float4 rsv = *(const float4*)&wsf[WS_ROW + ((size_t)p * N + i) * 4];
        float rc = rsv.x, l0 = rsv.y, ln0 = rsv.z;
        uint4 v = *(const uint4*)(sim + ((size_t)p * N + i) * N + c8);
        unsigned vv[4] = {v.x, v.y, v.z, v.w};
        float o[8];
        #pragma unroll
        for (int k = 0; k < 8; ++k) {
            float x = b2f((u16)(vv[k >> 1] >> ((k & 1) * 16)));
            float cA = ((const float*)&cs[0])[2 * k];
            float s1 = ((const float*)&cs[0])[2 * k + 1];
            float t = (x + rc) + (x + cA);
            o[k] = fmaxf(fmaxf(t, MASKVAL) + (l0 + s1), MASKVAL);
        }
        if (!head) {
            uint4 wv;
            wv.x = pk2(o[0], o[1]); wv.y = pk2(o[2], o[3]);
            wv.z = pk2(o[4], o[5]); wv.w = pk2(o[6], o[7]);
            *(uint4*)&stg[r][c8] = wv;
        } else {
            stg[r][c8 + 1] = f2b(o[0]);
            *(unsigned*)&stg[r][c8 + 2] = pk2(o[1], o[2]);
            *(unsigned*)&stg[r][c8 + 4] = pk2(o[3], o[4]);
            *(unsigned*)&stg[r][c8 + 6] = pk2(o[5], o[6]);
            stg[r][c8 + 8] = f2b(o[7]);
        }
        if (tid == 255) stg[r][2048 + head] = f2b(ln0);   // border col
    }
    __syncthreads();
    #pragma unroll
    for (int r = 0; r < 8; ++r) {
        int i = strip * 8 + r;
        int head = (p + i) & 1;
        size_t B0 = ((size_t)p * NO + i) * NO;
        size_t U0 = (B0 + head) >> 1;
        const unsigned* srow32 = (const unsigned*)&stg[r][0];
        #pragma unroll
        for (int k = 0; k < 4; ++k) {
            int kk = k * 256 + tid;
            up[U0 + kk] = srow32[kk + head];
        }
        if (tid == 0) {
            if (head) out[B0] = stg[r][1];        // out col 0 (slot 0+1)
            else      out[B0 + N] = stg[r][2048]; // border col (slot 2048)
        }
    }
}

extern "C" void kernel_launch(void* const* d_in, const int* in_sizes, int n_in,
                              void* d_out, int out_size, void* d_ws, size_t ws_size,
                              hipStream_t stream) {
    const float* desc    = (const float*)d_in[0];
    const int*   mask    = (const int*)d_in[1];
    const float* proj_w  = (const float*)d_in[2];
    const float* proj_b  = (const float*)d_in[3];
    const float* match_w = (const float*)d_in[4];
    const float* match_b = (const float*)d_in[5];
    u16*   out = (u16*)d_out;
    float* wsf = (float*)d_ws;
    u16*   mdesc = (u16*)((char*)d_ws + (size_t)WS_F_COUNT * sizeof(float));
    u16*   simw  = mdesc + (size_t)16 * N * D;   // PAIRS*N*N bf16, 2048-stride aligned

    k_proj_mfma<<<dim3(256, 2),    256, 0, stream>>>(desc, proj_w, proj_b, match_w, match_b, mdesc, wsf);
    k_sim_mfma <<<dim3(16, 16, 8), 256, 0, stream>>>(mdesc, mask, simw, wsf);
    k_red      <<<dim3(8, 8),      256, 0, stream>>>(wsf);
    k_final    <<<dim3(257, 8),    256, 0, stream>>>(out, simw, wsf);
}